// Round 4
// baseline (245.025 us; speedup 1.0000x reference)
//
#include <hip/hip_runtime.h>
#include <math.h>

// Capsule dynamic routing, MI355X. Round 9: shorten the per-block critical path.
// R8 post-mortem: s_load V = SMEM latency chain (SGPR-starved), LDS atomics +
// TROW=64 halved parallelism. R9: (1) wave-local staging -> wave w stages rows
// 8w..8w+7 and phase 1 reads ONLY own rows, gated by per-wave vmcnt(0) (no
// barrier between staging and ph1); (2) makeV merged into route (o-fold + V
// transform run under the u-DMA shadow; lgkm-only raw s_barriers keep the DMA
// in flight); (3) Op ping-pong (A->B->A) removes the RAW hazard; 4 dispatches.
// V reads: broadcast/32-bank conflict-free. u reads: 2-way per 16-lane phase.

#define BATCH 64
#define NN    2048
#define KD    128
#define JCAP  10
#define DCAP  16
#define JDIM  160
#define EPSQ  1e-7f
#define NT    64      // tiles of TROW rows
#define TROW  32
#define GSTR  132     // padded k-stride of G in LDS

// ws layout (floats): OpA[64][64][160] @0 ; OpB @655360
#define WS_OPA 0
#define WS_OPB (BATCH * NT * JDIM)

__device__ __forceinline__ void gload16(const float* g, void* l) {
  __builtin_amdgcn_global_load_lds(
      (const __attribute__((address_space(1))) void*)g,
      (__attribute__((address_space(3))) void*)l, 16, 0, 0);
}

// ---- K1: iteration 0 (c uniform 0.1): per-tile colsum -> fold through W ----
__global__ __launch_bounds__(256) void f_iter0(const float* __restrict__ u,
                                               const float* __restrict__ W,
                                               float* __restrict__ Op) {
  const int b = blockIdx.y, tile = blockIdx.x, t = threadIdx.x;
  __shared__ __align__(16) float4 red[256];
  __shared__ float S_s[KD];
  const int c = t & 31, rg = t >> 5;        // 8 row-groups x 4 rows
  const float* p = u + (((size_t)(b * NN + tile * TROW + rg * 4)) << 7) + (c << 2);
  float4 a = make_float4(0.f, 0.f, 0.f, 0.f);
#pragma unroll
  for (int r = 0; r < 4; ++r) {
    const float4 w4 = *(const float4*)(p + ((size_t)r << 7));
    a.x += w4.x; a.y += w4.y; a.z += w4.z; a.w += w4.w;
  }
  red[t] = a;
  __syncthreads();
  if (t < 32) {
    float4 s4 = red[t];
#pragma unroll
    for (int g = 1; g < 8; ++g) {
      const float4 w4 = red[g * 32 + t];
      s4.x += w4.x; s4.y += w4.y; s4.z += w4.z; s4.w += w4.w;
    }
    s4.x *= 0.1f; s4.y *= 0.1f; s4.z *= 0.1f; s4.w *= 0.1f;
    *(float4*)&S_s[t * 4] = s4;              // G[j][k] = 0.1*S[k] for all j
  }
  __syncthreads();
  if (t < JDIM) {
    float acc = 0.f;
#pragma unroll 8
    for (int k = 0; k < KD; ++k) acc += S_s[k] * W[k * JDIM + t];
    Op[((size_t)(b * NT) + tile) * JDIM + t] = acc;
  }
}

// ---- K2/K3: routing iteration: o-fold -> V -> logits -> softmax -> G -> W ----
__global__ __launch_bounds__(256) void f_route(const float* __restrict__ u,
                                               const float* __restrict__ OpIn,
                                               const float* __restrict__ W,
                                               float* __restrict__ OpOut) {
  const int b = blockIdx.y, tile = blockIdx.x, t = threadIdx.x;
  const int r0 = tile * TROW;
  __shared__ __align__(16) float4 u4[TROW * 32];     // 16 KB, XOR-swizzled
  __shared__ __align__(16) float4 Vs4[JCAP * 32];    // 5 KB, linear
  __shared__ __align__(16) float Cs[JCAP][TROW];     // 1.25 KB
  __shared__ __align__(16) float GpPl[JCAP * GSTR];  // 5.28 KB (ph1: Pl[10][32])
  __shared__ float o_s[JDIM];

  const int w = t >> 6, l = t & 63;

  // (1) issue u DMA first: wave w stages rows 8w..8w+7 (linear dest,
  //     inverse-swizzled per-lane source; logical L at pos L^(r&7))
  {
    const float* ub = u + (((size_t)(b * NN + r0)) << 7);
#pragma unroll
    for (int p = 0; p < 4; ++p) {
      const int df = (w << 8) + (p << 6);            // wave-uniform dest base
      const int s = df + l;
      const int r = s >> 5, pos = s & 31;
      const int L = pos ^ (r & 7);
      gload16(ub + (((size_t)r) << 7) + (L << 2), &u4[df]);
    }
  }

  // (2) under the DMA shadow: fold OpIn -> o_s (t<160), L2-hot loads
  if (t < JDIM) {
    const float* p = OpIn + (size_t)b * NT * JDIM + t;
    float s = 0.f;
#pragma unroll 8
    for (int tl = 0; tl < NT; ++tl) s += p[tl * JDIM];
    o_s[t] = s;
  }
  asm volatile("s_waitcnt lgkmcnt(0)" ::: "memory");  // o_s visible; vmcnt NOT drained
  __builtin_amdgcn_s_barrier();

  // (3) V[j][k] = sum_d W[k][j*16+d]*o[j][d]; thread = (k = t&127, j-half)
  {
    const int k = t & 127, jh = (t >> 7) * 5;
    const float* wp = W + k * JDIM + jh * DCAP;      // 80 consecutive floats
#pragma unroll 1
    for (int jj = 0; jj < 5; ++jj) {
      float a = 0.f;
#pragma unroll
      for (int d = 0; d < DCAP; ++d)
        a += wp[jj * DCAP + d] * o_s[(jh + jj) * DCAP + d];
      ((float*)Vs4)[(jh + jj) * KD + k] = a;
    }
  }
  asm volatile("s_waitcnt lgkmcnt(0)" ::: "memory");  // Vs visible; DMA still in flight
  __builtin_amdgcn_s_barrier();
  asm volatile("s_waitcnt vmcnt(0)" ::: "memory");    // own-wave u DMA landed
  __builtin_amdgcn_sched_barrier(0);

  // (4) phase 1: logits for OWN rows. lane = (rx = l>>3 row, kq = l&7).
  //     u: 2-way per 16-lane phase; V: 32-bank exact / broadcast. k-reduce
  //     via 3 shfl_xor; lane kq==0 writes Pl[j][r].
  {
    const int rx = l >> 3, kq = l & 7;
    const int r = (w << 3) + rx;
    float4 ur[4];
#pragma unroll
    for (int c = 0; c < 4; ++c) ur[c] = u4[(r << 5) + ((c * 8 + kq) ^ rx)];
    float acc[JCAP];
#pragma unroll
    for (int j = 0; j < JCAP; ++j) {
      float a = 0.f;
#pragma unroll
      for (int c = 0; c < 4; ++c) {
        const float4 vv = Vs4[j * 32 + c * 8 + kq];
        a += ur[c].x * vv.x + ur[c].y * vv.y + ur[c].z * vv.z + ur[c].w * vv.w;
      }
      acc[j] = a;
    }
#pragma unroll
    for (int j = 0; j < JCAP; ++j) {
      acc[j] += __shfl_xor(acc[j], 1, 64);
      acc[j] += __shfl_xor(acc[j], 2, 64);
      acc[j] += __shfl_xor(acc[j], 4, 64);
    }
    if (kq == 0) {
#pragma unroll
      for (int j = 0; j < JCAP; ++j) GpPl[j * TROW + r] = acc[j];
    }
  }
  __syncthreads();

  // (5) softmax over j (one wave)
  if (t < TROW) {
    float lg[JCAP];
    float m = -1e30f;
#pragma unroll
    for (int j = 0; j < JCAP; ++j) { lg[j] = GpPl[j * TROW + t]; m = fmaxf(m, lg[j]); }
    float ss = 0.f;
#pragma unroll
    for (int j = 0; j < JCAP; ++j) { lg[j] = __expf(lg[j] - m); ss += lg[j]; }
    const float inv = 1.f / ss;
#pragma unroll
    for (int j = 0; j < JCAP; ++j) Cs[j][t] = lg[j] * inv;
  }
  __syncthreads();

  // (6) phase 2: G[j][k] = sum_r c[j][r]*u[r][k]; wave owns j-subset over ALL
  //     rows; lane = k-pair; swizzle term chalf^ri is compile-time per ri.
  {
    const int j0 = (w < 2) ? 3 * w : 2 * w + 2;     // {0,3,6,8}
    const int jn = (w < 2) ? 3 : 2;                 // {3,3,2,2}
    const int chalf = l >> 1, cin = (l & 1) << 1;   // k = 2*l
    float g0[3], g1[3];
#pragma unroll
    for (int jj = 0; jj < 3; ++jj) { g0[jj] = 0.f; g1[jj] = 0.f; }
#pragma unroll
    for (int o = 0; o < 4; ++o) {                   // row octaves
      float ua[8], uc[8];
#pragma unroll
      for (int ri = 0; ri < 8; ++ri) {
        const int r = o * 8 + ri;
        const float2 uu2 =
            *(const float2*)((const float*)&u4[(r << 5) + (chalf ^ ri)] + cin);
        ua[ri] = uu2.x; uc[ri] = uu2.y;
      }
#pragma unroll
      for (int jj = 0; jj < 3; ++jj) {
        if (jj < jn) {
          const float4 cA = *(const float4*)&Cs[j0 + jj][o * 8];
          const float4 cB = *(const float4*)&Cs[j0 + jj][o * 8 + 4];
          g0[jj] += cA.x * ua[0] + cA.y * ua[1] + cA.z * ua[2] + cA.w * ua[3]
                  + cB.x * ua[4] + cB.y * ua[5] + cB.z * ua[6] + cB.w * ua[7];
          g1[jj] += cA.x * uc[0] + cA.y * uc[1] + cA.z * uc[2] + cA.w * uc[3]
                  + cB.x * uc[4] + cB.y * uc[5] + cB.z * uc[6] + cB.w * uc[7];
        }
      }
    }
#pragma unroll
    for (int jj = 0; jj < 3; ++jj)
      if (jj < jn)
        *(float2*)&GpPl[(j0 + jj) * GSTR + 2 * l] = make_float2(g0[jj], g1[jj]);
  }
  __syncthreads();

  // (7) fold G through W -> per-tile o partials (GSTR pad: broadcast groups)
  if (t < JDIM) {
    const int j = t >> 4;
    const float* gj = GpPl + j * GSTR;
    float acc = 0.f;
#pragma unroll 8
    for (int k = 0; k < KD; ++k) acc += gj[k] * W[k * JDIM + t];
    OpOut[((size_t)(b * NT) + tile) * JDIM + t] = acc;
  }
}

// ---- K4: fold Op partials, squash, store ----
__global__ __launch_bounds__(192) void f_squash(const float* __restrict__ Op,
                                                float* __restrict__ out) {
  const int b = blockIdx.x, t = threadIdx.x;
  __shared__ float o_s[JDIM];
  __shared__ float sc[JCAP];
  if (t < JDIM) {
    float s = 0.f;
    const float* p = Op + (size_t)b * NT * JDIM + t;
#pragma unroll 8
    for (int tl = 0; tl < NT; ++tl) s += p[tl * JDIM];
    o_s[t] = s;
  }
  __syncthreads();
  if (t < JCAP) {
    float s2 = 0.f;
#pragma unroll
    for (int d = 0; d < DCAP; ++d) { const float x = o_s[t * DCAP + d]; s2 += x * x; }
    sc[t] = s2 / ((1.f + s2) * sqrtf(s2 + EPSQ));
  }
  __syncthreads();
  if (t < JDIM) out[b * JDIM + t] = o_s[t] * sc[t >> 4];
}

extern "C" void kernel_launch(void* const* d_in, const int* in_sizes, int n_in,
                              void* d_out, int out_size, void* d_ws, size_t ws_size,
                              hipStream_t stream) {
  const float* u = (const float*)d_in[0];   // (64,2048,128) fp32
  const float* W = (const float*)d_in[1];   // (128,160) fp32
  float* out = (float*)d_out;               // (64,10,16) fp32
  float* ws  = (float*)d_ws;

  float* OpA = ws + WS_OPA;
  float* OpB = ws + WS_OPB;
  f_iter0 <<<dim3(NT, BATCH), 256, 0, stream>>>(u, W, OpA);
  f_route <<<dim3(NT, BATCH), 256, 0, stream>>>(u, OpA, W, OpB);
  f_route <<<dim3(NT, BATCH), 256, 0, stream>>>(u, OpB, W, OpA);
  f_squash<<<BATCH, 192, 0, stream>>>(OpA, out);
}

// Round 6
// 168.706 us; speedup vs baseline: 1.4524x; 1.4524x over previous
//
#include <hip/hip_runtime.h>
#include <math.h>

// Capsule dynamic routing, MI355X. Round 11: R10 with the NT bug fixed.
// R10 post-mortem: NT=32 x TROW=32 covered only 1024 of 2048 rows -> absmax ~1.
// Structure (untested in R10) kept: route emits raw G partials to global
// (o = (sum_tiles G)@W is linear); fold kernels do the single G@W per (b,j).
//   - route: stage u(16KB,XOR-swz)+V(5KB) -> ph1 logits -> softmax -> ph2 G ->
//     coalesced Gp store. No in-block W-fold (was 128 FMA + 128 LDS + 128 W
//     loads per thread = the serial tail). LDS 26.25KB -> 6 blocks/CU.
//   - f_fold grid (j,b)=640 blocks: fold Gp over 64 tiles (coalesced, 2.5
//     blocks/CU pulls 21MB in ~4us) -> o[j] -> {V | squash->out}.
//   - Sp aliases Gp region (fold0 consumes Sp before route1 writes Gp).
// Chain: iter0(Sp) -> fold0(V) -> route(Gp) -> fold1(V) -> route(Gp) -> fold2(out).
// ws = Gp 21MB + V 0.33MB.

#define BATCH 64
#define NN    2048
#define KD    128
#define JCAP  10
#define DCAP  16
#define JDIM  160
#define EPSQ  1e-7f
#define NT    64      // tiles of TROW rows ; NT*TROW == NN
#define TROW  32

// ws layout (floats): Gp[64][64][10][128] @0 (Sp[64][64][128] aliases @0) ;
//                     V[64][10][128] @5242880
#define WS_GP 0
#define WS_V  (BATCH * NT * JCAP * KD)

__device__ __forceinline__ void gload16(const float* g, void* l) {
  __builtin_amdgcn_global_load_lds(
      (const __attribute__((address_space(1))) void*)g,
      (__attribute__((address_space(3))) void*)l, 16, 0, 0);
}

// ---- K1: per-tile colsum partials Sp[b][tile][k] ----
__global__ __launch_bounds__(256) void f_iter0(const float* __restrict__ u,
                                               float* __restrict__ Sp) {
  const int b = blockIdx.y, tile = blockIdx.x, t = threadIdx.x;
  __shared__ __align__(16) float4 red[256];
  const int c = t & 31, rg = t >> 5;        // 8 row-groups x 4 rows
  const float* p = u + (((size_t)(b * NN + tile * TROW + rg * 4)) << 7) + (c << 2);
  float4 a = make_float4(0.f, 0.f, 0.f, 0.f);
#pragma unroll
  for (int r = 0; r < 4; ++r) {
    const float4 w4 = *(const float4*)(p + ((size_t)r << 7));
    a.x += w4.x; a.y += w4.y; a.z += w4.z; a.w += w4.w;
  }
  red[t] = a;
  __syncthreads();
  if (t < 32) {
    float4 s4 = red[t];
#pragma unroll
    for (int g = 1; g < 8; ++g) {
      const float4 w4 = red[g * 32 + t];
      s4.x += w4.x; s4.y += w4.y; s4.z += w4.z; s4.w += w4.w;
    }
    *(float4*)&Sp[(size_t)(b * NT + tile) * KD + t * 4] = s4;
  }
}

// ---- K2/K4/K6: block (j,b): fold partials -> o[j] -> {V | squash-out} ----
// pass0: In=Sp (x0.1) ; pass1: In=Gp ; both write V. pass2: In=Gp, write out.
__global__ __launch_bounds__(128) void f_fold(const float* __restrict__ In,
                                              const float* __restrict__ W,
                                              float* __restrict__ Out, int pass) {
  const int j = blockIdx.x, b = blockIdx.y, t = threadIdx.x;
  __shared__ float g_s[KD];
  __shared__ float o_s[DCAP];
  if (pass == 0) {
    const float* p = In + (size_t)b * NT * KD + t;        // Sp[b][tl][t]
    float s = 0.f;
#pragma unroll 8
    for (int tl = 0; tl < NT; ++tl) s += p[(size_t)tl * KD];
    g_s[t] = s * 0.1f;
  } else {
    const float* p = In + ((size_t)(b * NT) * JCAP + j) * KD + t;  // Gp[b][tl][j][t]
    float s = 0.f;
#pragma unroll 8
    for (int tl = 0; tl < NT; ++tl) s += p[(size_t)tl * JCAP * KD];
    g_s[t] = s;
  }
  __syncthreads();
  if (t < DCAP) {
    // o[j][d] = sum_k G[j][k] * W[k][j*16+d]
    float a = 0.f;
#pragma unroll 8
    for (int k = 0; k < KD; ++k) a += g_s[k] * W[k * JDIM + j * DCAP + t];
    o_s[t] = a;
  }
  __syncthreads();
  if (pass < 2) {
    // V[b][j][k] = sum_d W[k][j*16+d] * o[j][d]; thread = k
    const float* wp = W + t * JDIM + j * DCAP;
    float a = 0.f;
#pragma unroll
    for (int d = 0; d < DCAP; ++d) a += wp[d] * o_s[d];
    Out[((size_t)(b * JCAP) + j) * KD + t] = a;
  } else if (t < DCAP) {
    float s2 = 0.f;
#pragma unroll
    for (int d = 0; d < DCAP; ++d) s2 += o_s[d] * o_s[d];
    const float sc = s2 / ((1.f + s2) * sqrtf(s2 + EPSQ));
    Out[(size_t)(b * JCAP + j) * DCAP + t] = o_s[t] * sc;
  }
}

// ---- K3/K5: routing pass: logits -> softmax_j -> G partials (global) ----
__global__ __launch_bounds__(256) void f_route(const float* __restrict__ u,
                                               const float* __restrict__ V,
                                               float* __restrict__ Gp) {
  const int b = blockIdx.y, tile = blockIdx.x, t = threadIdx.x;
  const int r0 = tile * TROW;
  __shared__ __align__(16) float4 u4[TROW * 32];        // 16 KB, XOR-swizzled
  __shared__ __align__(16) float4 Vs4[JCAP * 32];       // 5 KB, linear
  __shared__ __align__(16) float PlCs[4 * JCAP * TROW]; // 5 KB; Cs aliases [0..319]

  // stage u tile (swizzled source, linear dest) + V (linear) via DMA
  {
    const float* ub = u + (((size_t)(b * NN + r0)) << 7);
    const int wbase = t & 192;                      // wave base within block
#pragma unroll
    for (int p = 0; p < 4; ++p) {
      const int s = p * 256 + t;
      const int r = s >> 5, csl = s & 31;
      const int c = csl ^ (r & 7);                  // involution
      gload16(ub + (((size_t)r) << 7) + (c << 2), &u4[p * 256 + wbase]);
    }
    const float* vb = V + (((size_t)(b * JCAP)) << 7);
    gload16(vb + (t << 2), &Vs4[wbase]);
    if (t < 64) gload16(vb + ((256 + t) << 2), &Vs4[256]);
  }
  __syncthreads();   // drains vmcnt

  // phase 1: logits. thread = (row r, k-eighth q8); V reads are broadcasts.
  {
    const int r = t & 31, q8 = t >> 5;
    float acc[JCAP];
#pragma unroll
    for (int j = 0; j < JCAP; ++j) acc[j] = 0.f;
#pragma unroll
    for (int c4 = 0; c4 < 4; ++c4) {
      const float4 uu = u4[(r << 5) + ((q8 * 4 + c4) ^ (r & 7))];
#pragma unroll
      for (int j = 0; j < JCAP; ++j) {
        const float4 vv = Vs4[j * 32 + q8 * 4 + c4];
        acc[j] += uu.x * vv.x + uu.y * vv.y + uu.z * vv.z + uu.w * vv.w;
      }
    }
    // lane l and l^32 hold the paired k-eighth -> k-quarter per wave
#pragma unroll
    for (int j = 0; j < JCAP; ++j) acc[j] += __shfl_xor(acc[j], 32, 64);
    if ((t & 32) == 0) {
      const int q4 = t >> 6;                        // wave id = k-quarter
#pragma unroll
      for (int j = 0; j < JCAP; ++j) PlCs[(q4 * JCAP + j) * TROW + r] = acc[j];
    }
  }
  __syncthreads();
  if (t < TROW) {                                   // softmax over j (lane-local col)
    float lg[JCAP];
    float m = -1e30f;
#pragma unroll
    for (int j = 0; j < JCAP; ++j) {
      const float s = PlCs[j * TROW + t] + PlCs[(JCAP + j) * TROW + t]
                    + PlCs[(2 * JCAP + j) * TROW + t]
                    + PlCs[(3 * JCAP + j) * TROW + t];
      lg[j] = s; m = fmaxf(m, s);
    }
    float ss = 0.f;
#pragma unroll
    for (int j = 0; j < JCAP; ++j) { lg[j] = __expf(lg[j] - m); ss += lg[j]; }
    const float inv = 1.f / ss;
#pragma unroll
    for (int j = 0; j < JCAP; ++j) PlCs[j * TROW + t] = lg[j] * inv;  // Cs alias
  }
  __syncthreads();

  // phase 2: G[j][k] = sum_r c[j][r]*u[r][k]. Wave owns a j-subset over ALL
  // rows; lane = k-pair; swizzle term chalf^ri is compile-time per ri.
  {
    const int w = t >> 6, l = t & 63;
    const int j0 = (w < 2) ? 3 * w : 2 * w + 2;     // {0,3,6,8}
    const int jn = (w < 2) ? 3 : 2;                 // {3,3,2,2}
    const int chalf = l >> 1, cin = (l & 1) << 1;   // k = 2*l
    float g0[3], g1[3];
#pragma unroll
    for (int jj = 0; jj < 3; ++jj) { g0[jj] = 0.f; g1[jj] = 0.f; }
#pragma unroll
    for (int o = 0; o < 4; ++o) {                   // row octaves
      float ua[8], uc[8];
#pragma unroll
      for (int ri = 0; ri < 8; ++ri) {
        const int r = o * 8 + ri;
        const float2 uu2 =
            *(const float2*)((const float*)&u4[(r << 5) + (chalf ^ ri)] + cin);
        ua[ri] = uu2.x; uc[ri] = uu2.y;
      }
#pragma unroll
      for (int jj = 0; jj < 3; ++jj) {
        if (jj < jn) {
          const float4 cA = *(const float4*)&PlCs[(j0 + jj) * TROW + o * 8];
          const float4 cB = *(const float4*)&PlCs[(j0 + jj) * TROW + o * 8 + 4];
          g0[jj] += cA.x * ua[0] + cA.y * ua[1] + cA.z * ua[2] + cA.w * ua[3]
                  + cB.x * ua[4] + cB.y * ua[5] + cB.z * ua[6] + cB.w * ua[7];
          g1[jj] += cA.x * uc[0] + cA.y * uc[1] + cA.z * uc[2] + cA.w * uc[3]
                  + cB.x * uc[4] + cB.y * uc[5] + cB.z * uc[6] + cB.w * uc[7];
        }
      }
    }
    float* gb = Gp + ((size_t)(b * NT + tile)) * JCAP * KD;
#pragma unroll
    for (int jj = 0; jj < 3; ++jj)
      if (jj < jn)
        *(float2*)&gb[(j0 + jj) * KD + 2 * l] = make_float2(g0[jj], g1[jj]);
  }
}

extern "C" void kernel_launch(void* const* d_in, const int* in_sizes, int n_in,
                              void* d_out, int out_size, void* d_ws, size_t ws_size,
                              hipStream_t stream) {
  const float* u = (const float*)d_in[0];   // (64,2048,128) fp32
  const float* W = (const float*)d_in[1];   // (128,160) fp32
  float* out = (float*)d_out;               // (64,10,16) fp32
  float* ws  = (float*)d_ws;

  float* Gp = ws + WS_GP;   // Sp aliases this region (consumed before Gp写)
  float* V  = ws + WS_V;
  f_iter0 <<<dim3(NT, BATCH), 256, 0, stream>>>(u, Gp);
  f_fold  <<<dim3(JCAP, BATCH), 128, 0, stream>>>(Gp, W, V, 0);
  f_route <<<dim3(NT, BATCH), 256, 0, stream>>>(u, V, Gp);
  f_fold  <<<dim3(JCAP, BATCH), 128, 0, stream>>>(Gp, W, V, 1);
  f_route <<<dim3(NT, BATCH), 256, 0, stream>>>(u, V, Gp);
  f_fold  <<<dim3(JCAP, BATCH), 128, 0, stream>>>(Gp, W, out, 2);
}